// Round 13
// baseline (72.644 us; speedup 1.0000x reference)
//
#include <hip/hip_runtime.h>
#include <math.h>
#include <stdint.h>

#define NN 8192
#define DD 1024
#define KT 2048   // 2*D
#define HH 100
#define HP 128    // padded hidden
#define LCAP 512
#define NB 32
#define NSL 4             // K slices
#define KSL 512           // K per slice
#define NBD 8             // 64-k bodies per slice

typedef short bf16x8 __attribute__((ext_vector_type(8)));
typedef short bf16x4 __attribute__((ext_vector_type(4)));
typedef float f32x4 __attribute__((ext_vector_type(4)));

__device__ __forceinline__ short f2bf(float f) {
    uint32_t u = __builtin_bit_cast(uint32_t, f);
    u += 0x7FFF + ((u >> 16) & 1);   // round-to-nearest-even
    return (short)(u >> 16);
}

// W1 fp32 [2048][100] -> w1p packed fragments:
// w1p[((c32*8 + tile)*64 + lane)*8 + j] = bf16(W1[c32*32 + (lane>>4)*8 + j][tile*16 + (lane&15)])
// Block 0 zeroes compaction counters.
__global__ __launch_bounds__(256) void prep_w1p(const float* __restrict__ W1,
                                                short* __restrict__ w1p,
                                                int* __restrict__ cnt1,
                                                int* __restrict__ cnt0)
{
    __shared__ float ld[32][104];
    const int t  = threadIdx.x;
    if (blockIdx.x == 0 && t < 64) {
        if (t < 32) cnt1[t] = 0; else cnt0[t - 32] = 0;
    }
    const int k0 = blockIdx.x * 32;          // 64 blocks
    for (int i = t; i < 32 * HH; i += 256) {
        const int kk = i / HH, cc = i - kk * HH;
        ld[kk][cc] = W1[(size_t)(k0 + kk) * HH + cc];
    }
    __syncthreads();
    for (int idx = t; idx < 512; idx += 256) {
        const int tt = idx >> 6, l = idx & 63;
        const int lr = l & 15, lg = l >> 4;
        const int col = tt * 16 + lr;
        bf16x8 r;
#pragma unroll
        for (int j = 0; j < 8; ++j)
            r[j] = (col < HH) ? f2bf(ld[lg * 8 + j][col]) : (short)0;
        *(bf16x8*)(w1p + ((size_t)(blockIdx.x * 8 + tt) * 64 + l) * 8) = r;
    }
}

// Split-K GEMM, M-tile 64: grid 512 = 128 mt x 4 slices (XCD-chunk swizzled).
// 512 thr / 8 waves = 4 row-groups x 2 col-halves. B K-slice (128 KB packed)
// staged once in LDS (1 barrier); 8-body barrier-free loop; fp32 partials out.
__global__ __launch_bounds__(512) void encoder_partial(
    const float* __restrict__ q, const float* __restrict__ x,
    const short* __restrict__ w1p, float* __restrict__ part)
{
    __shared__ short Bs[NBD * 8192];   // 128 KB
    const int t   = threadIdx.x;
    const int hw  = blockIdx.x;
    const int bid = (hw & 7) * 64 + (hw >> 3);   // XCD chunk swizzle (512%8==0)
    const int mt    = bid >> 2;        // 0..127 -> rows mt*64..+64
    const int slice = bid & 3;         // K quarter
    const int w  = t >> 6;             // wave 0..7
    const int l  = t & 63;
    const int lr = l & 15;
    const int lg = l >> 4;
    const int rg = w & 3;              // row-group (16 rows)
    const int ch = w >> 2;             // col half (64 cols)

    // ---- stage B slice to LDS (coalesced 16B per thread x 16) ----
    {
        const short* src = w1p + (size_t)slice * (NBD * 8192);
#pragma unroll
        for (int i = 0; i < 16; ++i) {
            const int e = (i * 512 + t) * 8;
            *(bf16x8*)&Bs[e] = *(const bf16x8*)(src + e);
        }
    }
    // A base: slice 0,1 in q; 2,3 in x
    const int row = mt * 64 + rg * 16 + lr;
    const float* arow = ((slice < 2) ? q : x)
        + (size_t)row * DD + (slice & 1) * KSL + lg * 8;
    __syncthreads();   // single barrier before epilogue

    f32x4 acc[4];
#pragma unroll
    for (int i = 0; i < 4; ++i) acc[i] = (f32x4)0.f;

    auto cvt8 = [](const float4& a, const float4& b) {
        bf16x8 s;
        s[0]=f2bf(a.x); s[1]=f2bf(a.y); s[2]=f2bf(a.z); s[3]=f2bf(a.w);
        s[4]=f2bf(b.x); s[5]=f2bf(b.y); s[6]=f2bf(b.z); s[7]=f2bf(b.w);
        return s;
    };
#define LOADA(c, u0, u1, u2, u3)               \
    { const float* p_ = arow + (c) * 64;       \
      u0 = *(const float4*)p_;                 \
      u1 = *(const float4*)(p_ + 4);           \
      u2 = *(const float4*)(p_ + 32);          \
      u3 = *(const float4*)(p_ + 36); }

#define BODY(c, u0, u1, u2, u3)                                               \
    { bf16x8 a0 = cvt8(u0, u1), a1 = cvt8(u2, u3);                            \
      const short* bb = &Bs[(c) * 8192 + ch * 4 * 512 + l * 8];               \
      _Pragma("unroll")                                                       \
      for (int tt = 0; tt < 4; ++tt) {                                        \
          bf16x8 f0 = *(const bf16x8*)(bb + tt * 512);                        \
          bf16x8 f1 = *(const bf16x8*)(bb + tt * 512 + 4096);                 \
          acc[tt] = __builtin_amdgcn_mfma_f32_16x16x32_bf16(a0, f0, acc[tt], 0,0,0); \
          acc[tt] = __builtin_amdgcn_mfma_f32_16x16x32_bf16(a1, f1, acc[tt], 0,0,0); \
      } }

    float4 u0,u1,u2,u3, v0,v1,v2,v3;
    LOADA(0, u0,u1,u2,u3);
#pragma unroll
    for (int c = 0; c < NBD; c += 2) {
        { const int cn = (c + 1 < NBD) ? c + 1 : 0; LOADA(cn, v0,v1,v2,v3); }
        BODY(c, u0,u1,u2,u3);
        { const int cn = (c + 2 < NBD) ? c + 2 : 0; LOADA(cn, u0,u1,u2,u3); }
        BODY(c + 1, v0,v1,v2,v3);
    }

    // ---- store fp32 partials: part[slice][row][col] ----
    float* pp = part + ((size_t)slice * NN + (size_t)(mt * 64 + rg * 16)) * HP + ch * 64;
#pragma unroll
    for (int tt = 0; tt < 4; ++tt)
#pragma unroll
        for (int r = 0; r < 4; ++r)
            pp[(lg * 4 + r) * HP + tt * 16 + lr] = acc[tt][r];
#undef LOADA
#undef BODY
}

// Phase B (verified in R10): 512 blocks x 256 thr; 16 rows/block. Sum 4 slices,
// bias+relu+W2, 16-lane shuffle reduce, compact into per-batch pos/neg lists.
__global__ __launch_bounds__(256) void reduce_score(
    const float* __restrict__ part,
    const float* __restrict__ b1, const float* __restrict__ W2,
    const float* __restrict__ b2,
    const int* __restrict__ bidx, const int* __restrict__ y,
    float* __restrict__ sp, float* __restrict__ sn,
    int* __restrict__ cnt1, int* __restrict__ cnt0)
{
    const int t   = threadIdx.x;
    const int row = t >> 4;           // 0..15
    const int cg  = t & 15;           // col group (8 cols)
    const int c0  = cg * 8;
    const int r0  = blockIdx.x * 16;
    const float* pr = part + ((size_t)(r0 + row)) * HP + c0;
    f32x4 s0 = (f32x4)0.f, s1 = (f32x4)0.f;
#pragma unroll
    for (int sl = 0; sl < NSL; ++sl) {
        const float* p = pr + (size_t)sl * NN * HP;
        s0 += *(const f32x4*)p;
        s1 += *(const f32x4*)(p + 4);
    }
    float acc = 0.f;
#pragma unroll
    for (int j = 0; j < 4; ++j) {
        const int ca = c0 + j, cb = c0 + 4 + j;
        const float ba = (ca < HH) ? b1[ca] : 0.f;
        const float wa = (ca < HH) ? W2[ca] : 0.f;
        const float bb = (cb < HH) ? b1[cb] : 0.f;
        const float wb = (cb < HH) ? W2[cb] : 0.f;
        acc = fmaf(fmaxf(s0[j] + ba, 0.f), wa, acc);
        acc = fmaf(fmaxf(s1[j] + bb, 0.f), wb, acc);
    }
    acc += __shfl_xor(acc, 1);
    acc += __shfl_xor(acc, 2);
    acc += __shfl_xor(acc, 4);
    acc += __shfl_xor(acc, 8);
    if (cg == 0) {
        const float sv = acc + b2[0];
        const int i = r0 + row;
        const int g = bidx[i];
        if (y[i]) {
            int idx = atomicAdd(&cnt1[g], 1);
            if (idx < LCAP) sp[g * LCAP + idx] = sv;
        } else {
            int idx = atomicAdd(&cnt0[g], 1);
            if (idx < LCAP) sn[g * LCAP + idx] = sv;
        }
    }
}

// grid = NB*8 blocks; block (g, sl) handles pos indices p ≡ sl (mod 8).
__global__ __launch_bounds__(256) void pairsum_kernel(
    const float* __restrict__ sp, const float* __restrict__ sn,
    const int* __restrict__ cnt1, const int* __restrict__ cnt0,
    float* __restrict__ partial)
{
    __shared__ float lsn[LCAP];
    __shared__ float lsp[64];
    __shared__ float wsum[4];
    const int g  = blockIdx.x >> 3;
    const int sl = blockIdx.x & 7;
    const int t  = threadIdx.x;
    const int n1 = min(cnt1[g], LCAP);
    const int n0 = min(cnt0[g], LCAP);
    for (int j = t; j < n0; j += 256) lsn[j] = sn[g * LCAP + j];
    const int np = (n1 > sl) ? ((n1 - sl + 7) >> 3) : 0;
    for (int j = t; j < np; j += 256) lsp[j] = sp[g * LCAP + sl + j * 8];
    __syncthreads();
    float acc = 0.f;
    const int total = np * n0;
    for (int u = t; u < total; u += 256) {
        const int ip = u / n0;
        const int j  = u - ip * n0;
        const float d  = lsn[j] - lsp[ip];          // s_neg - s_pos
        const float ad = fabsf(d);
        const float z  = __builtin_exp2f(-ad * 1.44269504f);
        acc += fmaxf(d, 0.f) + __builtin_log2f(1.f + z) * 0.69314718f;
    }
#pragma unroll
    for (int off = 32; off > 0; off >>= 1) acc += __shfl_xor(acc, off, 64);
    const int wid = t >> 6, lane = t & 63;
    if (lane == 0) wsum[wid] = acc;
    __syncthreads();
    if (t == 0) partial[blockIdx.x] = wsum[0] + wsum[1] + wsum[2] + wsum[3];
}

__global__ __launch_bounds__(256) void finalize_kernel(
    const float* __restrict__ partial,
    const int* __restrict__ cnt1, const int* __restrict__ cnt0,
    float* __restrict__ out)
{
    __shared__ float ws_[4], wc_[4];
    const int t = threadIdx.x;
    float sv = partial[t];   // 256 entries
    float cv = 0.f;
    if (t < NB) cv = (float)min(cnt1[t], LCAP) * (float)min(cnt0[t], LCAP);
#pragma unroll
    for (int off = 32; off > 0; off >>= 1) {
        sv += __shfl_xor(sv, off, 64);
        cv += __shfl_xor(cv, off, 64);
    }
    const int wid = t >> 6, lane = t & 63;
    if (lane == 0) { ws_[wid] = sv; wc_[wid] = cv; }
    __syncthreads();
    if (t == 0)
        out[0] = (ws_[0] + ws_[1] + ws_[2] + ws_[3]) /
                 (wc_[0] + wc_[1] + wc_[2] + wc_[3]);
}

extern "C" void kernel_launch(void* const* d_in, const int* in_sizes, int n_in,
                              void* d_out, int out_size, void* d_ws, size_t ws_size,
                              hipStream_t stream)
{
    const int*   b  = (const int*)d_in[0];
    const float* q  = (const float*)d_in[1];
    const float* x  = (const float*)d_in[2];
    const int*   y  = (const int*)d_in[3];
    const float* W1 = (const float*)d_in[4];
    const float* b1 = (const float*)d_in[5];
    const float* W2 = (const float*)d_in[6];
    const float* b2 = (const float*)d_in[7];
    float* out = (float*)d_out;

    char* base = (char*)d_ws;
    short* w1p     = (short*)base;                          // 512 KB packed B
    float* sp      = (float*)(base + 524288);               // 64 KB
    float* sn      = (float*)(base + 524288 + 65536);       // 64 KB
    int*   cnt1    = (int*)(base + 524288 + 131072);        // 128 B
    int*   cnt0    = cnt1 + NB;                             // 128 B
    float* partial = (float*)(base + 524288 + 131072 + 256);// 1 KB
    float* part    = (float*)(base + 1048576);              // 16 MB fp32 partials

    prep_w1p<<<KT / 32, 256, 0, stream>>>(W1, w1p, cnt1, cnt0);
    encoder_partial<<<(NN / 64) * NSL, 512, 0, stream>>>(q, x, w1p, part);
    reduce_score<<<NN / 16, 256, 0, stream>>>(part, b1, W2, b2,
                                              b, y, sp, sn, cnt1, cnt0);
    pairsum_kernel<<<NB * 8, 256, 0, stream>>>(sp, sn, cnt1, cnt0, partial);
    finalize_kernel<<<1, 256, 0, stream>>>(partial, cnt1, cnt0, out);
}